// Round 6
// baseline (216.535 us; speedup 1.0000x reference)
//
#include <hip/hip_runtime.h>
#include <hip/hip_bf16.h>
#include <hip/hip_cooperative_groups.h>

namespace cg = cooperative_groups;

// MaskedContrastiveLoss: loss = 0.5*[mean_i(rowLSE_i - pos_i) + mean_j(colLSE_j - pos_j)]
// logits = (A @ B^T) * (1/0.07), A,B: [256, 65536] fp32, L2-normalized rows.
//
// SINGLE-NODE graph (ledger: 1-node ~5us overhead vs ~90-120us for any
// multi-node graph): one cooperative kernel, no memset. Block 0 zeroes the
// counter page, one grid.sync publishes it (clean caches -> cheap), then:
//   GEMM (verbatim from 172us baseline) -> partials
//   arrival: RELEASE fetch_add on 8 split cachelines (no single-line storm)
//   finalizers (bid >= nblk-256): relaxed-poll + acquire fence; R2's proven
//   row body (logits + rowLSE - 2*pos), split-line barrier, R2's col body,
//   8 split float atomicAdd accumulators (R5 lesson: per-block plain slots
//   false-share on non-coherent XCD L2s and LOSE updates - atomics only),
//   leader block sums -> out.

#define D_DIM 65536
#define B_DIM 256
#define LDK 72  // padded LDS row stride (elements) to break bank conflicts

constexpr float TEMP = 1.0f / 0.07f;

typedef short short8 __attribute__((ext_vector_type(8)));
typedef float floatx4 __attribute__((ext_vector_type(4)));

__device__ inline unsigned short f2bf(float f) {
  unsigned u = __builtin_bit_cast(unsigned, f);
  unsigned rounding = 0x7fffu + ((u >> 16) & 1u);  // RNE (inputs are finite/normal)
  return (unsigned short)((u + rounding) >> 16);
}

__device__ inline void st_bf16x4(unsigned short* dst, float4 v) {
  uint2 u;
  u.x = (unsigned)f2bf(v.x) | ((unsigned)f2bf(v.y) << 16);
  u.y = (unsigned)f2bf(v.z) | ((unsigned)f2bf(v.w) << 16);
  *(uint2*)dst = u;
}

// ctr layout (u32 indices, 8 groups x 128B lines):
//   ctr[g*32 + 0] : arrival counter, group g      (sums to nblk)
//   ctr[g*32 + 8] : logits barrier counter        (sums to 256)
//   ctr[g*32 +16] : finale counter                (sums to 256)
//   ctr[g*32 +24] : float accumulator (as float)  (8-way split)
__global__ __launch_bounds__(256, 2) void mega(
    const float* __restrict__ A, const float* __restrict__ Bm,
    float* __restrict__ partials, float* __restrict__ logits,
    unsigned* __restrict__ ctr, float* __restrict__ out, int Kc, int C) {
  const int bid = blockIdx.x;
  const int nblk = gridDim.x;
  const int t = threadIdx.x;

  // zero the counter page; publish to all blocks (caches clean: cheap sync)
  if (bid == 0) ctr[t] = 0u;
  cg::this_grid().sync();

  const int mt = (bid & 1) * 128;
  const int nt = ((bid >> 1) & 1) * 128;
  const int chunk = bid >> 2;
  const size_t k0 = (size_t)chunk * (size_t)Kc;

  __shared__ unsigned short As[128][LDK];
  __shared__ unsigned short Bs[128][LDK];

  const int lane = t & 63;
  const int w = t >> 6;          // wave 0..3
  const int wm = (w & 1) * 64;   // wave sub-tile origin
  const int wn = (w >> 1) * 64;

  // global staging indexing: 16 threads cover one row's 64 floats (16 x float4)
  const int lr = t >> 4;          // base row 0..15 (+p*16)
  const int lc = (t & 15) * 4;    // col within BK=64

  const float* Abase = A + (size_t)(mt + lr) * D_DIM + k0 + lc;
  const float* Bbase = Bm + (size_t)(nt + lr) * D_DIM + k0 + lc;

  floatx4 acc[4][4];
#pragma unroll
  for (int mb = 0; mb < 4; ++mb)
#pragma unroll
    for (int nb = 0; nb < 4; ++nb) acc[mb][nb] = (floatx4)0.f;

  float4 ra[8], rb[8];
  const int nst = Kc >> 6;  // stages of BK=64

  // prefetch stage 0
#pragma unroll
  for (int p = 0; p < 8; ++p) {
    ra[p] = *(const float4*)(Abase + (size_t)p * 16 * D_DIM);
    rb[p] = *(const float4*)(Bbase + (size_t)p * 16 * D_DIM);
  }

  for (int s = 0; s < nst; ++s) {
    // convert + stage into LDS
#pragma unroll
    for (int p = 0; p < 8; ++p) {
      st_bf16x4(&As[lr + p * 16][lc], ra[p]);
      st_bf16x4(&Bs[lr + p * 16][lc], rb[p]);
    }
    __syncthreads();

    // issue next stage's global loads (overlap with MFMA below)
    if (s + 1 < nst) {
      const float* Ap = Abase + (size_t)(s + 1) * 64;
      const float* Bp = Bbase + (size_t)(s + 1) * 64;
#pragma unroll
      for (int p = 0; p < 8; ++p) {
        ra[p] = *(const float4*)(Ap + (size_t)p * 16 * D_DIM);
        rb[p] = *(const float4*)(Bp + (size_t)p * 16 * D_DIM);
      }
    }

    // MFMA over BK=64 (two K-steps of 32)
#pragma unroll
    for (int ks = 0; ks < 64; ks += 32) {
      short8 af[4], bf[4];
      const int ko = ks + (lane >> 4) * 8;
#pragma unroll
      for (int mb = 0; mb < 4; ++mb)
        af[mb] = *(const short8*)&As[wm + mb * 16 + (lane & 15)][ko];
#pragma unroll
      for (int nb = 0; nb < 4; ++nb)
        bf[nb] = *(const short8*)&Bs[wn + nb * 16 + (lane & 15)][ko];
#pragma unroll
      for (int mb = 0; mb < 4; ++mb)
#pragma unroll
        for (int nb = 0; nb < 4; ++nb)
          acc[mb][nb] = __builtin_amdgcn_mfma_f32_16x16x32_bf16(
              af[mb], bf[nb], acc[mb][nb], 0, 0, 0);
    }
    __syncthreads();
  }

  // epilogue: write partial tile. C/D layout: col=lane&15, row=(lane>>4)*4+reg
  float* outp = partials + (size_t)chunk * (B_DIM * B_DIM);
#pragma unroll
  for (int mb = 0; mb < 4; ++mb) {
#pragma unroll
    for (int nb = 0; nb < 4; ++nb) {
      const int gi0 = mt + wm + mb * 16 + ((lane >> 4) * 4);
      const int gj = nt + wn + nb * 16 + (lane & 15);
#pragma unroll
      for (int r = 0; r < 4; ++r)
        outp[(size_t)(gi0 + r) * B_DIM + gj] = acc[mb][nb][r];
    }
  }

  // ---- arrival: release publish on 8 split lines ----
  __syncthreads();  // drains partials stores (vmcnt(0) before barrier)
  if (t == 0)
    __hip_atomic_fetch_add(&ctr[(bid & 7) * 32], 1u, __ATOMIC_RELEASE,
                           __HIP_MEMORY_SCOPE_AGENT);
  const int fin0 = nblk - 256;
  if (bid < fin0) return;  // early blocks free their CU slots
  const int r = bid - fin0;  // 0..255: finalizer rank = output row/col index

  // wait for all arrivals: RELAXED polls (no cache maintenance), one acquire
  // fence at exit (invalidates stale L1/L2 before reading partials).
  if (t == 0) {
    for (;;) {
      unsigned sum = 0;
#pragma unroll
      for (int g = 0; g < 8; ++g)
        sum += __hip_atomic_load(&ctr[g * 32], __ATOMIC_RELAXED,
                                 __HIP_MEMORY_SCOPE_AGENT);
      if (sum >= (unsigned)nblk) break;
      __builtin_amdgcn_s_sleep(8);
    }
    __builtin_amdgcn_fence(__ATOMIC_ACQUIRE, "agent");
  }
  __syncthreads();

  // ---- row phase (R2 finalize_rows body): i = r, j = t ----
  __shared__ float posv;
  __shared__ float wsum[4];
  {
    const float* p = partials + (size_t)r * B_DIM + t;
    float s = 0.f;
#pragma unroll 32
    for (int c = 0; c < C; ++c) s += p[(size_t)c * (B_DIM * B_DIM)];
    const float lg = s * TEMP;
    logits[r * B_DIM + t] = lg;
    if (t == r) posv = lg;
    float e = expf(lg);  // |lg| <= 14.3 by Cauchy-Schwarz: no max-shift needed
#pragma unroll
    for (int off = 32; off > 0; off >>= 1) e += __shfl_down(e, off);
    if ((t & 63) == 0) wsum[t >> 6] = e;
  }
  __syncthreads();  // drains logits stores; wsum/posv visible
  float rterm = 0.f;
  if (t == 0) {
    rterm = logf(wsum[0] + wsum[1] + wsum[2] + wsum[3]) - 2.f * posv;
    // publish logits row (release -> wbl2), then barrier among finalizers
    __hip_atomic_fetch_add(&ctr[(bid & 7) * 32 + 8], 1u, __ATOMIC_RELEASE,
                           __HIP_MEMORY_SCOPE_AGENT);
    for (;;) {
      unsigned sum = 0;
#pragma unroll
      for (int g = 0; g < 8; ++g)
        sum += __hip_atomic_load(&ctr[g * 32 + 8], __ATOMIC_RELAXED,
                                 __HIP_MEMORY_SCOPE_AGENT);
      if (sum >= 256u) break;
      __builtin_amdgcn_s_sleep(8);
    }
    __builtin_amdgcn_fence(__ATOMIC_ACQUIRE, "agent");
  }
  __syncthreads();

  // ---- col phase (R2 finalize_cols body): j = r, i = t ----
  {
    float e = expf(logits[(size_t)t * B_DIM + r]);
#pragma unroll
    for (int off = 32; off > 0; off >>= 1) e += __shfl_down(e, off);
    if ((t & 63) == 0) wsum[t >> 6] = e;
  }
  __syncthreads();

  // ---- finale: 8-way split float atomics (NOT per-block slots: false
  // sharing on non-coherent XCD L2s loses updates - R5 lesson) ----
  if (t == 0) {
    const float cterm = logf(wsum[0] + wsum[1] + wsum[2] + wsum[3]);
    atomicAdd((float*)&ctr[(bid & 7) * 32 + 24], rterm + cterm);
    __hip_atomic_fetch_add(&ctr[(bid & 7) * 32 + 16], 1u, __ATOMIC_RELEASE,
                           __HIP_MEMORY_SCOPE_AGENT);
    if (r == 0) {  // deterministic leader
      for (;;) {
        unsigned sum = 0;
#pragma unroll
        for (int g = 0; g < 8; ++g)
          sum += __hip_atomic_load(&ctr[g * 32 + 16], __ATOMIC_RELAXED,
                                   __HIP_MEMORY_SCOPE_AGENT);
        if (sum >= 256u) break;
        __builtin_amdgcn_s_sleep(8);
      }
      __builtin_amdgcn_fence(__ATOMIC_ACQUIRE, "agent");
      float tot = 0.f;
#pragma unroll
      for (int g = 0; g < 8; ++g) tot += *(const float*)&ctr[g * 32 + 24];
      out[0] = tot * (0.5f / 256.f);
    }
  }
}

extern "C" void kernel_launch(void* const* d_in, const int* in_sizes, int n_in,
                              void* d_out, int out_size, void* d_ws, size_t ws_size,
                              hipStream_t stream) {
  (void)in_sizes; (void)n_in; (void)out_size;
  const float* A = (const float*)d_in[0];
  const float* Bm = (const float*)d_in[1];
  float* out = (float*)d_out;

  // ws layout: [logits 256*256 f32][partials C*256*256 f32][ctr 256 u32]
  const size_t per = (size_t)B_DIM * B_DIM * sizeof(float);  // 256 KB
  int C = 128;
  while (C > 1 && (size_t)(C + 1) * per + 1024 > ws_size) C >>= 1;

  // cooperative co-residency cap (host-only queries; cached)
  static int maxgrid = 0;
  if (maxgrid == 0) {
    int dev = 0, nb = 0, ncu = 0;
    hipGetDevice(&dev);
    hipOccupancyMaxActiveBlocksPerMultiprocessor(&nb, mega, 256, 0);
    hipDeviceGetAttribute(&ncu, hipDeviceAttributeMultiprocessorCount, dev);
    maxgrid = (nb > 0 && ncu > 0) ? nb * ncu : 512;
  }
  while (4 * C > maxgrid && C > 1) C >>= 1;  // grid must be fully co-resident
  int Kc = D_DIM / C;

  float* logits = (float*)d_ws;
  float* partials = (float*)d_ws + (size_t)B_DIM * B_DIM;
  unsigned* ctr = (unsigned*)(partials + (size_t)C * B_DIM * B_DIM);

  void* args[] = {(void*)&A,      (void*)&Bm,  (void*)&partials,
                  (void*)&logits, (void*)&ctr, (void*)&out,
                  (void*)&Kc,     (void*)&C};
  hipLaunchCooperativeKernel(mega, dim3(4 * C), dim3(256), args, 0, stream);
}

// Round 7
// 174.725 us; speedup vs baseline: 1.2393x; 1.2393x over previous
//
#include <hip/hip_runtime.h>
#include <hip/hip_bf16.h>

// MaskedContrastiveLoss: loss = 0.5*[mean_i(rowLSE_i - pos_i) + mean_j(colLSE_j - pos_j)]
// logits = (A @ B^T) * (1/0.07), A,B: [256, 65536] fp32, L2-normalized rows.
//
// Structure = R2's proven 4-dispatch pipeline (best: 163.7us), with the GEMM
// re-tiled for occupancy: grid was 512 = 2 blocks/CU (the binding limit;
// VGPR/LDS allowed 4+), leaving nothing to run during each stage's
// vmcnt(0)+barrier drain. Now 8 sub-tiles (64x128) per K-chunk -> grid 1024,
// LDS 27.6KB/block -> 4-5 blocks/CU co-resident.
// Fusion/coop/spin designs (R1,R3-R6) all regressed: ~100us per-iteration
// harness overhead is fixed, and resident spinners dilute the GEMM.

#define D_DIM 65536
#define B_DIM 256
#define LDK 72  // padded LDS row stride (elements) to break bank conflicts

constexpr float TEMP = 1.0f / 0.07f;

typedef short short8 __attribute__((ext_vector_type(8)));
typedef float floatx4 __attribute__((ext_vector_type(4)));

__device__ inline unsigned short f2bf(float f) {
  unsigned u = __builtin_bit_cast(unsigned, f);
  unsigned rounding = 0x7fffu + ((u >> 16) & 1u);  // RNE (inputs are finite/normal)
  return (unsigned short)((u + rounding) >> 16);
}

__device__ inline void st_bf16x4(unsigned short* dst, float4 v) {
  uint2 u;
  u.x = (unsigned)f2bf(v.x) | ((unsigned)f2bf(v.y) << 16);
  u.y = (unsigned)f2bf(v.z) | ((unsigned)f2bf(v.w) << 16);
  *(uint2*)dst = u;
}

// grid = 8*C blocks; block = 256 threads (4 waves).
// bid -> (mt in {0,64,128,192}, nt in {0,128}, K-chunk). Tile: 64x128.
__global__ __launch_bounds__(256, 4) void gemm_splitk(
    const float* __restrict__ A, const float* __restrict__ Bm,
    float* __restrict__ partials, int Kc) {
  const int bid = blockIdx.x;
  const int sub = bid & 7;
  const int mt = (sub & 3) * 64;
  const int nt = (sub >> 2) * 128;
  const int chunk = bid >> 3;
  const size_t k0 = (size_t)chunk * (size_t)Kc;

  __shared__ unsigned short As[64][LDK];
  __shared__ unsigned short Bs[128][LDK];

  const int t = threadIdx.x;
  const int lane = t & 63;
  const int w = t >> 6;          // wave 0..3
  const int wm = (w & 1) * 32;   // wave sub-tile origin in M (0/32)
  const int wn = (w >> 1) * 64;  // wave sub-tile origin in N (0/64)

  // global staging indexing: 16 threads cover one row's 64 floats (16 x float4)
  const int lr = t >> 4;          // base row 0..15 (+p*16)
  const int lc = (t & 15) * 4;    // col within BK=64

  const float* Abase = A + (size_t)(mt + lr) * D_DIM + k0 + lc;
  const float* Bbase = Bm + (size_t)(nt + lr) * D_DIM + k0 + lc;

  floatx4 acc[2][4];
#pragma unroll
  for (int mb = 0; mb < 2; ++mb)
#pragma unroll
    for (int nb = 0; nb < 4; ++nb) acc[mb][nb] = (floatx4)0.f;

  float4 ra[4], rb[8];
  const int nst = Kc >> 6;  // stages of BK=64

  // prefetch stage 0
#pragma unroll
  for (int p = 0; p < 4; ++p)
    ra[p] = *(const float4*)(Abase + (size_t)p * 16 * D_DIM);
#pragma unroll
  for (int p = 0; p < 8; ++p)
    rb[p] = *(const float4*)(Bbase + (size_t)p * 16 * D_DIM);

  for (int s = 0; s < nst; ++s) {
    // convert + stage into LDS
#pragma unroll
    for (int p = 0; p < 4; ++p) st_bf16x4(&As[lr + p * 16][lc], ra[p]);
#pragma unroll
    for (int p = 0; p < 8; ++p) st_bf16x4(&Bs[lr + p * 16][lc], rb[p]);
    __syncthreads();

    // issue next stage's global loads (overlap with MFMA below)
    if (s + 1 < nst) {
      const float* Ap = Abase + (size_t)(s + 1) * 64;
      const float* Bp = Bbase + (size_t)(s + 1) * 64;
#pragma unroll
      for (int p = 0; p < 4; ++p)
        ra[p] = *(const float4*)(Ap + (size_t)p * 16 * D_DIM);
#pragma unroll
      for (int p = 0; p < 8; ++p)
        rb[p] = *(const float4*)(Bp + (size_t)p * 16 * D_DIM);
    }

    // MFMA over BK=64 (two K-steps of 32)
#pragma unroll
    for (int ks = 0; ks < 64; ks += 32) {
      short8 af[2], bf[4];
      const int ko = ks + (lane >> 4) * 8;
#pragma unroll
      for (int mb = 0; mb < 2; ++mb)
        af[mb] = *(const short8*)&As[wm + mb * 16 + (lane & 15)][ko];
#pragma unroll
      for (int nb = 0; nb < 4; ++nb)
        bf[nb] = *(const short8*)&Bs[wn + nb * 16 + (lane & 15)][ko];
#pragma unroll
      for (int mb = 0; mb < 2; ++mb)
#pragma unroll
        for (int nb = 0; nb < 4; ++nb)
          acc[mb][nb] = __builtin_amdgcn_mfma_f32_16x16x32_bf16(
              af[mb], bf[nb], acc[mb][nb], 0, 0, 0);
    }
    __syncthreads();
  }

  // epilogue: write partial tile. C/D layout: col=lane&15, row=(lane>>4)*4+reg
  float* outp = partials + (size_t)chunk * (B_DIM * B_DIM);
#pragma unroll
  for (int mb = 0; mb < 2; ++mb) {
#pragma unroll
    for (int nb = 0; nb < 4; ++nb) {
      const int gi0 = mt + wm + mb * 16 + ((lane >> 4) * 4);
      const int gj = nt + wn + nb * 16 + (lane & 15);
#pragma unroll
      for (int r = 0; r < 4; ++r)
        outp[(size_t)(gi0 + r) * B_DIM + gj] = acc[mb][nb][r];
    }
  }
}

// block i: logits row i = TEMP * sum_c partials[c][i][:]; write logits row;
// rowout[i] = rowLSE_i - 2*pos_i. No atomics; unroll-32 gives 4 latency
// batches over the C=128 chain instead of 32.
__global__ void finalize_rows(const float* __restrict__ partials,
                              float* __restrict__ logits,
                              float* __restrict__ rowout, int C) {
  const int i = blockIdx.x;
  const int j = threadIdx.x;
  const float* p = partials + (size_t)i * B_DIM + j;
  float s = 0.f;
#pragma unroll 32
  for (int c = 0; c < C; ++c) s += p[(size_t)c * (B_DIM * B_DIM)];
  const float lg = s * TEMP;
  logits[i * B_DIM + j] = lg;

  __shared__ float posv;
  if (j == i) posv = lg;

  float e = expf(lg);  // |lg| <= 14.3 by Cauchy-Schwarz: no max-shift needed
#pragma unroll
  for (int off = 32; off > 0; off >>= 1) e += __shfl_down(e, off);
  __shared__ float wsum[4];
  if ((j & 63) == 0) wsum[j >> 6] = e;
  __syncthreads();
  if (j == 0) {
    const float tot = wsum[0] + wsum[1] + wsum[2] + wsum[3];
    rowout[i] = logf(tot) - 2.f * posv;
  }
}

// block j: colout[j] = colLSE_j from finalized logits. No atomics.
__global__ void finalize_cols(const float* __restrict__ logits,
                              float* __restrict__ colout) {
  const int j = blockIdx.x;
  const int i = threadIdx.x;
  float e = expf(logits[(size_t)i * B_DIM + j]);
#pragma unroll
  for (int off = 32; off > 0; off >>= 1) e += __shfl_down(e, off);
  __shared__ float wsum[4];
  if ((i & 63) == 0) wsum[i >> 6] = e;
  __syncthreads();
  if (i == 0) {
    const float tot = wsum[0] + wsum[1] + wsum[2] + wsum[3];
    colout[j] = logf(tot);
  }
}

// 1 block: out = (0.5/256) * sum_i(rowout[i] + colout[i]). Writes out
// directly (no memset dispatch needed).
__global__ void finalize_out(const float* __restrict__ rowout,
                             const float* __restrict__ colout,
                             float* __restrict__ out) {
  const int t = threadIdx.x;
  float v = rowout[t] + colout[t];
#pragma unroll
  for (int off = 32; off > 0; off >>= 1) v += __shfl_down(v, off);
  __shared__ float wsum[4];
  if ((t & 63) == 0) wsum[t >> 6] = v;
  __syncthreads();
  if (t == 0) out[0] = (wsum[0] + wsum[1] + wsum[2] + wsum[3]) * (0.5f / 256.f);
}

extern "C" void kernel_launch(void* const* d_in, const int* in_sizes, int n_in,
                              void* d_out, int out_size, void* d_ws, size_t ws_size,
                              hipStream_t stream) {
  (void)in_sizes; (void)n_in; (void)out_size;
  const float* A = (const float*)d_in[0];
  const float* Bm = (const float*)d_in[1];
  float* out = (float*)d_out;

  // ws layout: [logits: 256*256 f32][partials: C * 256*256 f32][rowout 256][colout 256]
  const size_t per = (size_t)B_DIM * B_DIM * sizeof(float);  // 256 KB
  int C = 128;
  while (C > 1 && (size_t)(C + 1) * per + 2 * B_DIM * sizeof(float) > ws_size)
    C >>= 1;
  const int Kc = D_DIM / C;

  float* logits = (float*)d_ws;
  float* partials = (float*)d_ws + (size_t)B_DIM * B_DIM;
  float* rowout = partials + (size_t)C * B_DIM * B_DIM;
  float* colout = rowout + B_DIM;

  gemm_splitk<<<8 * C, 256, 0, stream>>>(A, Bm, partials, Kc);
  finalize_rows<<<B_DIM, B_DIM, 0, stream>>>(partials, logits, rowout, C);
  finalize_cols<<<B_DIM, B_DIM, 0, stream>>>(logits, colout);
  finalize_out<<<1, B_DIM, 0, stream>>>(rowout, colout, out);
}

// Round 8
// 162.433 us; speedup vs baseline: 1.3331x; 1.0757x over previous
//
#include <hip/hip_runtime.h>
#include <hip/hip_bf16.h>

// MaskedContrastiveLoss: loss = 0.5*[mean_i(rowLSE_i - pos_i) + mean_j(colLSE_j - pos_j)]
// logits = (A @ B^T) * (1/0.07), A,B: [256, 65536] fp32, L2-normalized rows.
//
// Structure = R2's proven 4-dispatch pipeline (best: 163.7us). This round
// restructures ONLY the gemm inner loop to kill the __syncthreads vmcnt(0)
// drain (R7 showed occupancy isn't the limit: 2x occupancy -> only 1.16x BW,
// and fetch inflation ate it; R2 tiling restored):
//   - raw s_barrier + explicit lgkmcnt(0) (no vmcnt drain at barriers)
//   - 2-deep register prefetch (named E/O sets - rule: no runtime indexing)
//   - double-buffered LDS (72KB, still 2 blocks/CU at grid 512)
// Loads are issued a full iteration before use -> HBM latency hidden,
// continuous load issue instead of per-stage bursts.

#define D_DIM 65536
#define B_DIM 256
#define LDK 72  // padded LDS row stride (elements) to break bank conflicts

constexpr float TEMP = 1.0f / 0.07f;

typedef short short8 __attribute__((ext_vector_type(8)));
typedef float floatx4 __attribute__((ext_vector_type(4)));

__device__ inline unsigned short f2bf(float f) {
  unsigned u = __builtin_bit_cast(unsigned, f);
  unsigned rounding = 0x7fffu + ((u >> 16) & 1u);  // RNE (inputs are finite/normal)
  return (unsigned short)((u + rounding) >> 16);
}

__device__ inline void st_bf16x4(unsigned short* dst, float4 v) {
  uint2 u;
  u.x = (unsigned)f2bf(v.x) | ((unsigned)f2bf(v.y) << 16);
  u.y = (unsigned)f2bf(v.z) | ((unsigned)f2bf(v.w) << 16);
  *(uint2*)dst = u;
}

// grid = 4*C blocks; block = 256 threads (4 waves).
// blockIdx.x -> (mt in {0,128}, nt in {0,128}, K-chunk). Tile 128x128.
__global__ __launch_bounds__(256, 2) void gemm_splitk(
    const float* __restrict__ A, const float* __restrict__ Bm,
    float* __restrict__ partials, int Kc) {
  const int bid = blockIdx.x;
  const int mt = (bid & 1) * 128;
  const int nt = ((bid >> 1) & 1) * 128;
  const int chunk = bid >> 2;
  const size_t k0 = (size_t)chunk * (size_t)Kc;

  __shared__ unsigned short As[2][128][LDK];
  __shared__ unsigned short Bs[2][128][LDK];

  const int t = threadIdx.x;
  const int lane = t & 63;
  const int w = t >> 6;          // wave 0..3
  const int wm = (w & 1) * 64;   // wave sub-tile origin
  const int wn = (w >> 1) * 64;

  // global staging indexing: 16 threads cover one row's 64 floats (16 x float4)
  const int lr = t >> 4;          // base row 0..15 (+p*16)
  const int lc = (t & 15) * 4;    // col within BK=64

  const float* Abase = A + (size_t)(mt + lr) * D_DIM + k0 + lc;
  const float* Bbase = Bm + (size_t)(nt + lr) * D_DIM + k0 + lc;

  floatx4 acc[4][4];
#pragma unroll
  for (int mb = 0; mb < 4; ++mb)
#pragma unroll
    for (int nb = 0; nb < 4; ++nb) acc[mb][nb] = (floatx4)0.f;

  float4 raE[8], rbE[8], raO[8], rbO[8];  // even/odd stage register sets
  const int nst = Kc >> 6;  // stages of BK=64; Kc=1024/C*64 -> always even

#define LOADSET(ra, rb, S)                                                 \
  {                                                                        \
    const float* Ap_ = Abase + (size_t)(S)*64;                             \
    const float* Bp_ = Bbase + (size_t)(S)*64;                             \
    _Pragma("unroll") for (int p = 0; p < 8; ++p) {                        \
      ra[p] = *(const float4*)(Ap_ + (size_t)p * 16 * D_DIM);              \
      rb[p] = *(const float4*)(Bp_ + (size_t)p * 16 * D_DIM);              \
    }                                                                      \
  }

#define STAGE(ra, rb, BUF)                                                 \
  {                                                                        \
    _Pragma("unroll") for (int p = 0; p < 8; ++p) {                        \
      st_bf16x4(&As[BUF][lr + p * 16][lc], ra[p]);                         \
      st_bf16x4(&Bs[BUF][lr + p * 16][lc], rb[p]);                         \
    }                                                                      \
  }

#define MFMA_BUF(BUF)                                                      \
  {                                                                        \
    _Pragma("unroll") for (int ks = 0; ks < 64; ks += 32) {                \
      short8 af[4], bf[4];                                                 \
      const int ko = ks + (lane >> 4) * 8;                                 \
      _Pragma("unroll") for (int mb = 0; mb < 4; ++mb)                     \
          af[mb] = *(const short8*)&As[BUF][wm + mb * 16 + (lane & 15)][ko]; \
      _Pragma("unroll") for (int nb = 0; nb < 4; ++nb)                     \
          bf[nb] = *(const short8*)&Bs[BUF][wn + nb * 16 + (lane & 15)][ko]; \
      _Pragma("unroll") for (int mb = 0; mb < 4; ++mb)                     \
          _Pragma("unroll") for (int nb = 0; nb < 4; ++nb)                 \
              acc[mb][nb] = __builtin_amdgcn_mfma_f32_16x16x32_bf16(       \
                  af[mb], bf[nb], acc[mb][nb], 0, 0, 0);                   \
    }                                                                      \
  }

  // 2-deep prologue
  LOADSET(raE, rbE, 0)
  LOADSET(raO, rbO, 1)

  for (int s = 0; s < nst; s += 2) {
    // ---- even stage: buffer 0 ----
    STAGE(raE, rbE, 0)  // compiler inserts counted vmcnt wait for raE/rbE
    asm volatile("s_waitcnt lgkmcnt(0)" ::: "memory");  // ds_writes visible
    __builtin_amdgcn_s_barrier();   // raw: NO vmcnt(0) drain
    __builtin_amdgcn_sched_barrier(0);
    if (s + 2 < nst) LOADSET(raE, rbE, s + 2)  // in flight across barriers
    MFMA_BUF(0)
    // safety: our buf1 writes below race no one: every wave passed bar(s),
    // i.e. finished its MFMA(s-1) reads of buf1 (lgkm waited before use).

    // ---- odd stage: buffer 1 ----
    STAGE(raO, rbO, 1)
    asm volatile("s_waitcnt lgkmcnt(0)" ::: "memory");
    __builtin_amdgcn_s_barrier();
    __builtin_amdgcn_sched_barrier(0);
    if (s + 3 < nst) LOADSET(raO, rbO, s + 3)
    MFMA_BUF(1)
  }

  // epilogue: write partial tile. C/D layout: col=lane&15, row=(lane>>4)*4+reg
  float* outp = partials + (size_t)chunk * (B_DIM * B_DIM);
#pragma unroll
  for (int mb = 0; mb < 4; ++mb) {
#pragma unroll
    for (int nb = 0; nb < 4; ++nb) {
      const int gi0 = mt + wm + mb * 16 + ((lane >> 4) * 4);
      const int gj = nt + wn + nb * 16 + (lane & 15);
#pragma unroll
      for (int r = 0; r < 4; ++r)
        outp[(size_t)(gi0 + r) * B_DIM + gj] = acc[mb][nb][r];
    }
  }
}

// block i: logits row i = TEMP * sum_c partials[c][i][:]; write logits row;
// rowout[i] = rowLSE_i - 2*pos_i. No atomics; unroll-32 gives 4 latency
// batches over the C=128 chain instead of 32.
__global__ void finalize_rows(const float* __restrict__ partials,
                              float* __restrict__ logits,
                              float* __restrict__ rowout, int C) {
  const int i = blockIdx.x;
  const int j = threadIdx.x;
  const float* p = partials + (size_t)i * B_DIM + j;
  float s = 0.f;
#pragma unroll 32
  for (int c = 0; c < C; ++c) s += p[(size_t)c * (B_DIM * B_DIM)];
  const float lg = s * TEMP;
  logits[i * B_DIM + j] = lg;

  __shared__ float posv;
  if (j == i) posv = lg;

  float e = expf(lg);  // |lg| <= 14.3 by Cauchy-Schwarz: no max-shift needed
#pragma unroll
  for (int off = 32; off > 0; off >>= 1) e += __shfl_down(e, off);
  __shared__ float wsum[4];
  if ((j & 63) == 0) wsum[j >> 6] = e;
  __syncthreads();
  if (j == 0) {
    const float tot = wsum[0] + wsum[1] + wsum[2] + wsum[3];
    rowout[i] = logf(tot) - 2.f * posv;
  }
}

// block j: colout[j] = colLSE_j from finalized logits. No atomics.
__global__ void finalize_cols(const float* __restrict__ logits,
                              float* __restrict__ colout) {
  const int j = blockIdx.x;
  const int i = threadIdx.x;
  float e = expf(logits[(size_t)i * B_DIM + j]);
#pragma unroll
  for (int off = 32; off > 0; off >>= 1) e += __shfl_down(e, off);
  __shared__ float wsum[4];
  if ((i & 63) == 0) wsum[i >> 6] = e;
  __syncthreads();
  if (i == 0) {
    const float tot = wsum[0] + wsum[1] + wsum[2] + wsum[3];
    colout[j] = logf(tot);
  }
}

// 1 block: out = (0.5/256) * sum_i(rowout[i] + colout[i]). Writes out
// directly (no memset dispatch needed).
__global__ void finalize_out(const float* __restrict__ rowout,
                             const float* __restrict__ colout,
                             float* __restrict__ out) {
  const int t = threadIdx.x;
  float v = rowout[t] + colout[t];
#pragma unroll
  for (int off = 32; off > 0; off >>= 1) v += __shfl_down(v, off);
  __shared__ float wsum[4];
  if ((t & 63) == 0) wsum[t >> 6] = v;
  __syncthreads();
  if (t == 0) out[0] = (wsum[0] + wsum[1] + wsum[2] + wsum[3]) * (0.5f / 256.f);
}

extern "C" void kernel_launch(void* const* d_in, const int* in_sizes, int n_in,
                              void* d_out, int out_size, void* d_ws, size_t ws_size,
                              hipStream_t stream) {
  (void)in_sizes; (void)n_in; (void)out_size;
  const float* A = (const float*)d_in[0];
  const float* Bm = (const float*)d_in[1];
  float* out = (float*)d_out;

  // ws layout: [logits: 256*256 f32][partials: C * 256*256 f32][rowout 256][colout 256]
  const size_t per = (size_t)B_DIM * B_DIM * sizeof(float);  // 256 KB
  int C = 128;
  while (C > 1 && (size_t)(C + 1) * per + 2 * B_DIM * sizeof(float) > ws_size)
    C >>= 1;
  const int Kc = D_DIM / C;

  float* logits = (float*)d_ws;
  float* partials = (float*)d_ws + (size_t)B_DIM * B_DIM;
  float* rowout = partials + (size_t)C * B_DIM * B_DIM;
  float* colout = rowout + B_DIM;

  gemm_splitk<<<4 * C, 256, 0, stream>>>(A, Bm, partials, Kc);
  finalize_rows<<<B_DIM, B_DIM, 0, stream>>>(partials, logits, rowout, C);
  finalize_cols<<<B_DIM, B_DIM, 0, stream>>>(logits, colout);
  finalize_out<<<1, B_DIM, 0, stream>>>(rowout, colout, out);
}